// Round 13
// baseline (148.557 us; speedup 1.0000x reference)
//
#include <hip/hip_runtime.h>
#include <math.h>

#define B_SIZE 8192
#define D_SIZE 256
#define N_CLS 1024
#define CLS_CAP 64
#define PCAP 256
#define ALPHA 2.0f
#define BETA 50.0f
#define BASE 0.5f
#define MARGIN 0.1f

#define TM 128
#define TK 32
#define NT (B_SIZE / TM)            // 64 tiles per dim
#define NBLK (NT * (NT + 1) / 2)    // 2080 triangular tiles
#define NEG_BLKS 512                // 2 blocks/CU exactly
#define TPB 4                       // tiles/block; first 32 blocks take a 5th
#define NCONV (B_SIZE * D_SIZE / 1024)   // 2048 convert blocks

typedef __attribute__((ext_vector_type(8))) __bf16 bf16x8;
typedef __attribute__((ext_vector_type(4))) float f32x4;

__device__ __forceinline__ unsigned int enc_f32(float f) {
    unsigned int u = __float_as_uint(f);
    return (u & 0x80000000u) ? ~u : (u | 0x80000000u);
}
__device__ __forceinline__ float dec_f32(unsigned int e) {
    unsigned int u = (e & 0x80000000u) ? (e ^ 0x80000000u) : ~e;
    return __uint_as_float(u);
}

__device__ __forceinline__ unsigned short f2bf(float x) {
    unsigned int u = __float_as_uint(x);
    u += 0x7FFFu + ((u >> 16) & 1u);   // RNE
    return (unsigned short)(u >> 16);
}

__device__ __forceinline__ void glds16(const unsigned short* g, const unsigned char* l) {
    __builtin_amdgcn_global_load_lds((const __attribute__((address_space(1))) void*)g,
                                     (__attribute__((address_space(3))) void*)l, 16, 0, 0);
}

// decode unordered pair index p -> (a, b), 0 <= b < a
__device__ __forceinline__ void pair_decode(int p, int& a, int& b) {
    a = (int)((1.0f + sqrtf(1.0f + 8.0f * (float)p)) * 0.5f);
    while (a * (a - 1) / 2 > p) --a;
    while ((a + 1) * a / 2 <= p) ++a;
    b = p - a * (a - 1) / 2;
}

// ---- K1: fused class-blocks (0..N_CLS) + convert blocks (N_CLS..) ----
__global__ __launch_bounds__(256) void conv_pos_kernel(
    const float* __restrict__ emb, const int* __restrict__ labels,
    unsigned short* __restrict__ embb,
    float* __restrict__ pos_min, float* __restrict__ psims,
    int* __restrict__ cls_cnt, int* __restrict__ cls_rows) {
    int t = threadIdx.x;
    if (blockIdx.x >= N_CLS) {
        int i = ((blockIdx.x - N_CLS) * 256 + t) * 4;
        float4 v = *(const float4*)(&emb[i]);
        ushort4 o;
        o.x = f2bf(v.x); o.y = f2bf(v.y); o.z = f2bf(v.z); o.w = f2bf(v.w);
        *(ushort4*)(&embb[i]) = o;
        return;
    }
    int cls = blockIdx.x;
    __shared__ int rs[CLS_CAP];
    __shared__ unsigned int smin[CLS_CAP];
    __shared__ int lcnt;
    if (t == 0) lcnt = 0;
    if (t < CLS_CAP) smin[t] = 0xFF800000u;  // enc(+inf)
    __syncthreads();
    const int4* lab4 = (const int4*)labels;
    for (int i = t; i < B_SIZE / 4; i += 256) {
        int4 L = lab4[i];
        if (L.x == cls) { int p = atomicAdd(&lcnt, 1); if (p < CLS_CAP) rs[p] = 4 * i; }
        if (L.y == cls) { int p = atomicAdd(&lcnt, 1); if (p < CLS_CAP) rs[p] = 4 * i + 1; }
        if (L.z == cls) { int p = atomicAdd(&lcnt, 1); if (p < CLS_CAP) rs[p] = 4 * i + 2; }
        if (L.w == cls) { int p = atomicAdd(&lcnt, 1); if (p < CLS_CAP) rs[p] = 4 * i + 3; }
    }
    __syncthreads();
    int c = min(lcnt, CLS_CAP);
    if (t == 0) cls_cnt[cls] = c;
    if (t < c) cls_rows[cls * CLS_CAP + t] = rs[t];
    int np = c * (c - 1) / 2;
    for (int base = 0; base < np * 8; base += 256) {
        int slot = base + t;
        if (slot < np * 8) {
            int p = slot >> 3, l = slot & 7;   // 8 aligned lanes per pair
            int a, b; pair_decode(p, a, b);
            const float4* pa = (const float4*)(emb + (size_t)rs[a] * D_SIZE) + l * 8;
            const float4* pb = (const float4*)(emb + (size_t)rs[b] * D_SIZE) + l * 8;
            float s = 0.0f;
#pragma unroll
            for (int k = 0; k < 8; ++k) {
                float4 x = pa[k], y = pb[k];
                s = fmaf(x.x, y.x, fmaf(x.y, y.y, fmaf(x.z, y.z, fmaf(x.w, y.w, s))));
            }
            s += __shfl_xor(s, 1, 64);
            s += __shfl_xor(s, 2, 64);
            s += __shfl_xor(s, 4, 64);
            if (l == 0) {
                if (p < PCAP) psims[cls * PCAP + p] = s;
                unsigned int e = enc_f32(s);
                atomicMin(&smin[a], e);
                atomicMin(&smin[b], e);
            }
        }
    }
    __syncthreads();
    if (t < c) pos_min[rs[t]] = dec_f32(smin[t]);
}

// ---- K2: the GEMM — 512 persistent-ish blocks, 4-5 tiles each, LDS dbuf
//      chained ACROSS tiles (next tile's chunk-0 staged during epilogue) ----
// part[k*B + row]: m-side writes k=bj (bj>=bi), n-side k=bi (bi<bj) -> each
// k written exactly once per row => no init, no atomics.
// C/D layout (16x16x32): col = lane&15, row = (lane>>4)*4 + reg  [m89/m91]
__global__ __launch_bounds__(256) void neg_kernel(
    const unsigned short* __restrict__ embb, const int* __restrict__ labels,
    const float* __restrict__ pos_min,
    float* __restrict__ part_sum, float* __restrict__ part_max)
{
    const int tid = threadIdx.x;
    const int lane = tid & 63;
    const int w = tid >> 6;
    const int wm = w >> 1, wn = w & 1;
    const int col = lane & 15;
    const int quad = lane >> 4;

    __shared__ unsigned char As[2][TM * 64];
    __shared__ unsigned char Bs[2][TM * 64];
    __shared__ int labm[2][TM];
    __shared__ int labn[2][TM];

    // staging lane geometry (tile-invariant)
    int srow[2], sco[2], lofs[2];
#pragma unroll
    for (int s = 0; s < 2; ++s) {
        int r = w * 32 + s * 16 + (lane >> 2);
        int c = (lane & 3) ^ ((r >> 1) & 3);
        srow[s] = r; sco[s] = c * 8; lofs[s] = r * 64;
    }
    int aoff[4], boff[4];
#pragma unroll
    for (int f = 0; f < 4; ++f) {
        int ra = wm * 64 + f * 16 + col;
        int rb = wn * 64 + f * 16 + col;
        aoff[f] = ra * 64 + ((quad ^ ((ra >> 1) & 3)) * 16);
        boff[f] = rb * 64 + ((quad ^ ((rb >> 1) & 3)) * 16);
    }

    // tile list: blockIdx + k*NEG_BLKS (k=0..3), first 32 blocks take a 5th
    int m0s[TPB + 1], n0s[TPB + 1];
    int ntile = TPB;
#pragma unroll
    for (int k = 0; k <= TPB; ++k) {
        int bt = (k < TPB) ? (blockIdx.x + k * NEG_BLKS) : (TPB * NEG_BLKS + blockIdx.x);
        if (k == TPB) {
            if (blockIdx.x < NBLK - TPB * NEG_BLKS) ntile = TPB + 1;
            else { m0s[k] = 0; n0s[k] = 0; continue; }
        }
        int bi = 0, rem = bt;
        while (rem >= NT - bi) { rem -= NT - bi; ++bi; }
        m0s[k] = bi * TM;
        n0s[k] = (bi + rem) * TM;
    }

    // prefetch tile 0 chunk 0 into stage 0
#pragma unroll
    for (int s = 0; s < 2; ++s) {
        glds16(embb + (size_t)(m0s[0] + srow[s]) * D_SIZE + sco[s], As[0] + lofs[s]);
        glds16(embb + (size_t)(n0s[0] + srow[s]) * D_SIZE + sco[s], Bs[0] + lofs[s]);
    }

    for (int tt = 0; tt < ntile; ++tt) {
        const int m0 = m0s[tt], n0 = n0s[tt];
        const int bi = m0 / TM, bj = n0 / TM;
        const bool isdiag = (bi == bj);
        const int pb = tt & 1;
        // labels into parity buffer (reads ordered by it=0 barrier below)
        if (tid < TM) labm[pb][tid] = labels[m0 + tid];
        else          labn[pb][tid - TM] = labels[n0 + tid - TM];

        const unsigned short* gA[2];
        const unsigned short* gB[2];
#pragma unroll
        for (int s = 0; s < 2; ++s) {
            gA[s] = embb + (size_t)(m0 + srow[s]) * D_SIZE + sco[s];
            gB[s] = embb + (size_t)(n0 + srow[s]) * D_SIZE + sco[s];
        }

        f32x4 acc[4][4];
#pragma unroll
        for (int fi = 0; fi < 4; ++fi)
#pragma unroll
            for (int fj = 0; fj < 4; ++fj)
                acc[fi][fj] = (f32x4){0.0f, 0.0f, 0.0f, 0.0f};

#pragma unroll
        for (int it = 0; it < D_SIZE / TK; ++it) {
            const int st = it & 1;
            __syncthreads();   // stage st's staging complete
            if (it + 1 < D_SIZE / TK) {
                const int k1 = (it + 1) * TK;
#pragma unroll
                for (int s = 0; s < 2; ++s) {
                    glds16(gA[s] + k1, As[st ^ 1] + lofs[s]);
                    glds16(gB[s] + k1, Bs[st ^ 1] + lofs[s]);
                }
            } else if (tt + 1 < ntile) {
                // chain: stage NEXT tile's chunk 0 into stage 0 (st^1 == 0);
                // its latency hides behind this tile's epilogue.
#pragma unroll
                for (int s = 0; s < 2; ++s) {
                    glds16(embb + (size_t)(m0s[tt + 1] + srow[s]) * D_SIZE + sco[s],
                           As[0] + lofs[s]);
                    glds16(embb + (size_t)(n0s[tt + 1] + srow[s]) * D_SIZE + sco[s],
                           Bs[0] + lofs[s]);
                }
            }
            bf16x8 af[4], bf[4];
#pragma unroll
            for (int f = 0; f < 4; ++f) {
                af[f] = __builtin_bit_cast(bf16x8, *(const uint4*)(As[st] + aoff[f]));
                bf[f] = __builtin_bit_cast(bf16x8, *(const uint4*)(Bs[st] + boff[f]));
            }
#pragma unroll
            for (int fi = 0; fi < 4; ++fi)
#pragma unroll
                for (int fj = 0; fj < 4; ++fj)
                    acc[fi][fj] = __builtin_amdgcn_mfma_f32_16x16x32_bf16(
                        af[fi], bf[fj], acc[fi][fj], 0, 0, 0);
        }

        // ---- epilogue (overlaps the in-flight next-tile staging) ----
        int ljv[4]; float pmc[4], nsn[4], nmx[4];
#pragma unroll
        for (int fj = 0; fj < 4; ++fj) {
            int cl = wn * 64 + fj * 16 + col;
            ljv[fj] = labn[pb][cl];
            pmc[fj] = pos_min[n0 + cl] - MARGIN;
            nsn[fj] = 0.0f;
            nmx[fj] = -__builtin_inff();
        }
#pragma unroll
        for (int fi = 0; fi < 4; ++fi) {
            int rl0 = wm * 64 + fi * 16 + quad * 4;
            int gi0 = m0 + rl0;
            int lir[4]; float pmr[4], msn[4], mmx[4];
#pragma unroll
            for (int r = 0; r < 4; ++r) {
                lir[r] = labm[pb][rl0 + r];
                pmr[r] = pos_min[gi0 + r] - MARGIN;
                msn[r] = 0.0f;
                mmx[r] = -__builtin_inff();
            }
#pragma unroll
            for (int fj = 0; fj < 4; ++fj) {
#pragma unroll
                for (int r = 0; r < 4; ++r) {
                    float s = acc[fi][fj][r];
                    if (lir[r] != ljv[fj]) {
                        float e = __expf(BETA * (s - BASE));
                        mmx[r] = fmaxf(mmx[r], s);
                        if (s > pmr[r]) msn[r] += e;
                        nmx[fj] = fmaxf(nmx[fj], s);
                        if (s > pmc[fj]) nsn[fj] += e;
                    }
                }
            }
#pragma unroll
            for (int m = 1; m < 16; m <<= 1) {
#pragma unroll
                for (int r = 0; r < 4; ++r) {
                    msn[r] += __shfl_xor(msn[r], m, 64);
                    mmx[r] = fmaxf(mmx[r], __shfl_xor(mmx[r], m, 64));
                }
            }
            if (col == 0) {
                *(float4*)(&part_sum[(size_t)bj * B_SIZE + gi0]) =
                    make_float4(msn[0], msn[1], msn[2], msn[3]);
                *(float4*)(&part_max[(size_t)bj * B_SIZE + gi0]) =
                    make_float4(mmx[0], mmx[1], mmx[2], mmx[3]);
            }
        }
        if (!isdiag) {
#pragma unroll
            for (int m = 16; m < 64; m <<= 1) {
#pragma unroll
                for (int fj = 0; fj < 4; ++fj) {
                    nsn[fj] += __shfl_xor(nsn[fj], m, 64);
                    nmx[fj] = fmaxf(nmx[fj], __shfl_xor(nmx[fj], m, 64));
                }
            }
            if (quad == 0) {
#pragma unroll
                for (int fj = 0; fj < 4; ++fj) {
                    int gj = n0 + wn * 64 + fj * 16 + col;
                    part_sum[(size_t)bi * B_SIZE + gj] = nsn[fj];
                    part_max[(size_t)bi * B_SIZE + gj] = nmx[fj];
                }
            }
        }
    }
}

// ---- K3: dense coalesced reduce of partials -> sneg/snm per row ----
__global__ __launch_bounds__(256) void reduce_kernel(
    const float* __restrict__ part_sum, const float* __restrict__ part_max,
    float* __restrict__ sneg, float* __restrict__ snm) {
    int row = blockIdx.x * 256 + threadIdx.x;
    float s0 = 0.f, s1 = 0.f, s2 = 0.f, s3 = 0.f;
    float m0 = -__builtin_inff(), m1 = m0, m2 = m0, m3 = m0;
#pragma unroll
    for (int k = 0; k < NT; k += 4) {
        s0 += part_sum[(size_t)(k + 0) * B_SIZE + row];
        s1 += part_sum[(size_t)(k + 1) * B_SIZE + row];
        s2 += part_sum[(size_t)(k + 2) * B_SIZE + row];
        s3 += part_sum[(size_t)(k + 3) * B_SIZE + row];
        m0 = fmaxf(m0, part_max[(size_t)(k + 0) * B_SIZE + row]);
        m1 = fmaxf(m1, part_max[(size_t)(k + 1) * B_SIZE + row]);
        m2 = fmaxf(m2, part_max[(size_t)(k + 2) * B_SIZE + row]);
        m3 = fmaxf(m3, part_max[(size_t)(k + 3) * B_SIZE + row]);
    }
    sneg[row] = (s0 + s1) + (s2 + s3);
    snm[row] = fmaxf(fmaxf(m0, m1), fmaxf(m2, m3));
}

// ---- K4: per-class sum_pos from cached sims + per-class term (plain stores) ----
__global__ __launch_bounds__(256) void final_kernel(
    const float* __restrict__ emb, const int* __restrict__ cls_cnt,
    const int* __restrict__ cls_rows, const float* __restrict__ psims,
    const float* __restrict__ sneg_g, const float* __restrict__ snm_g,
    float* __restrict__ cls_term, float* __restrict__ cls_valid) {
    int cls = blockIdx.x;
    __shared__ int rs[CLS_CAP];
    __shared__ float snm[CLS_CAP];
    __shared__ float ssum[CLS_CAP];
    int t = threadIdx.x;
    int c = min(cls_cnt[cls], CLS_CAP);
    if (t < CLS_CAP) ssum[t] = 0.0f;
    if (t < c) {
        rs[t] = cls_rows[cls * CLS_CAP + t];
        snm[t] = snm_g[rs[t]];
    }
    __syncthreads();
    int np = c * (c - 1) / 2;
    if (np <= PCAP) {
        for (int p = t; p < np; p += 256) {
            float s = psims[cls * PCAP + p];
            int a, b; pair_decode(p, a, b);
            float e = __expf(-ALPHA * (s - BASE));
            if (s - MARGIN < snm[a]) atomicAdd(&ssum[a], e);
            if (s - MARGIN < snm[b]) atomicAdd(&ssum[b], e);
        }
    } else {
        for (int base = 0; base < np * 8; base += 256) {
            int slot = base + t;
            if (slot < np * 8) {
                int p = slot >> 3, l = slot & 7;
                int a, b; pair_decode(p, a, b);
                const float4* pa = (const float4*)(emb + (size_t)rs[a] * D_SIZE) + l * 8;
                const float4* pb = (const float4*)(emb + (size_t)rs[b] * D_SIZE) + l * 8;
                float s = 0.0f;
#pragma unroll
                for (int k = 0; k < 8; ++k) {
                    float4 x = pa[k], y = pb[k];
                    s = fmaf(x.x, y.x, fmaf(x.y, y.y, fmaf(x.z, y.z, fmaf(x.w, y.w, s))));
                }
                s += __shfl_xor(s, 1, 64);
                s += __shfl_xor(s, 2, 64);
                s += __shfl_xor(s, 4, 64);
                if (l == 0) {
                    float e = __expf(-ALPHA * (s - BASE));
                    if (s - MARGIN < snm[a]) atomicAdd(&ssum[a], e);
                    if (s - MARGIN < snm[b]) atomicAdd(&ssum[b], e);
                }
            }
        }
    }
    __syncthreads();
    if (t < 64) {
        float term = 0.0f, valid = 0.0f;
        if (t < c) {
            float sp = ssum[t], sn = sneg_g[rs[t]];
            if (sp > 0.0f && sn > 0.0f) {
                term = log1pf(sp) * (1.0f / ALPHA) + log1pf(sn) * (1.0f / BETA);
                valid = 1.0f;
            }
        }
#pragma unroll
        for (int m = 1; m < 64; m <<= 1) {
            term += __shfl_xor(term, m, 64);
            valid += __shfl_xor(valid, m, 64);
        }
        if (t == 0) { cls_term[cls] = term; cls_valid[cls] = valid; }
    }
}

// ---- K5: fold 1024 class terms -> out ----
__global__ __launch_bounds__(256) void finalize_kernel(
    const float* __restrict__ cls_term, const float* __restrict__ cls_valid,
    float* __restrict__ out) {
    __shared__ float st[256];
    __shared__ float sc[256];
    int t = threadIdx.x;
    float tot = 0.0f, cnt = 0.0f;
#pragma unroll
    for (int i = 0; i < N_CLS / 256; ++i) {
        tot += cls_term[i * 256 + t];
        cnt += cls_valid[i * 256 + t];
    }
    st[t] = tot; sc[t] = cnt;
    __syncthreads();
    for (int s = 128; s > 0; s >>= 1) {
        if (t < s) { st[t] += st[t + s]; sc[t] += sc[t + s]; }
        __syncthreads();
    }
    if (t == 0) out[0] = st[0] / fmaxf(sc[0], 1.0f);
}

extern "C" void kernel_launch(void* const* d_in, const int* in_sizes, int n_in,
                              void* d_out, int out_size, void* d_ws, size_t ws_size,
                              hipStream_t stream) {
    const float* emb = (const float*)d_in[0];
    const int* labels = (const int*)d_in[1];
    float* out = (float*)d_out;

    // ws: embb 4MB | part_sum 2MB | part_max 2MB | psims 1MB | cls_rows 256KB |
    //     pos_min 32KB | sneg 32KB | snm 32KB | cls_term 4KB | cls_valid 4KB |
    //     cls_cnt 4KB
    unsigned short* embb = (unsigned short*)d_ws;
    float* part_sum = (float*)(embb + (size_t)B_SIZE * D_SIZE);
    float* part_max = part_sum + (size_t)NT * B_SIZE;
    float* psims = part_max + (size_t)NT * B_SIZE;
    int* cls_rows = (int*)(psims + (size_t)N_CLS * PCAP);
    float* pos_min = (float*)(cls_rows + N_CLS * CLS_CAP);
    float* sneg = pos_min + B_SIZE;
    float* snm = sneg + B_SIZE;
    float* cls_term = snm + B_SIZE;
    float* cls_valid = cls_term + N_CLS;
    int* cls_cnt = (int*)(cls_valid + N_CLS);

    conv_pos_kernel<<<dim3(N_CLS + NCONV), dim3(256), 0, stream>>>(
        emb, labels, embb, pos_min, psims, cls_cnt, cls_rows);
    neg_kernel<<<dim3(NEG_BLKS), dim3(256), 0, stream>>>(
        embb, labels, pos_min, part_sum, part_max);
    reduce_kernel<<<dim3(B_SIZE / 256), dim3(256), 0, stream>>>(
        part_sum, part_max, sneg, snm);
    final_kernel<<<dim3(N_CLS), dim3(256), 0, stream>>>(
        emb, cls_cnt, cls_rows, psims, sneg, snm, cls_term, cls_valid);
    finalize_kernel<<<dim3(1), dim3(256), 0, stream>>>(cls_term, cls_valid, out);
}

// Round 14
// 137.121 us; speedup vs baseline: 1.0834x; 1.0834x over previous
//
#include <hip/hip_runtime.h>
#include <math.h>

#define B_SIZE 8192
#define D_SIZE 256
#define N_CLS 1024
#define CLS_CAP 64
#define PCAP 256
#define ALPHA 2.0f
#define BETA 50.0f
#define BASE 0.5f
#define MARGIN 0.1f

// neg GEMM tiling: 128x128 tile, BK=32 double-buffered, 4 waves (2x2 of 64x64)
// LDS = exactly 32 KB (labels read direct from L2) -> 5 blocks/CU
#define TM 128
#define TK 32
#define NT (B_SIZE / TM)            // 64 tiles per dim
#define NBLK (NT * (NT + 1) / 2)    // 2080 triangular tiles
#define NCONV (B_SIZE * D_SIZE / 1024)   // 2048 convert blocks

typedef __attribute__((ext_vector_type(8))) __bf16 bf16x8;
typedef __attribute__((ext_vector_type(4))) float f32x4;

__device__ __forceinline__ unsigned int enc_f32(float f) {
    unsigned int u = __float_as_uint(f);
    return (u & 0x80000000u) ? ~u : (u | 0x80000000u);
}
__device__ __forceinline__ float dec_f32(unsigned int e) {
    unsigned int u = (e & 0x80000000u) ? (e ^ 0x80000000u) : ~e;
    return __uint_as_float(u);
}

__device__ __forceinline__ unsigned short f2bf(float x) {
    unsigned int u = __float_as_uint(x);
    u += 0x7FFFu + ((u >> 16) & 1u);   // RNE
    return (unsigned short)(u >> 16);
}

__device__ __forceinline__ void glds16(const unsigned short* g, const unsigned char* l) {
    __builtin_amdgcn_global_load_lds((const __attribute__((address_space(1))) void*)g,
                                     (__attribute__((address_space(3))) void*)l, 16, 0, 0);
}

// decode unordered pair index p -> (a, b), 0 <= b < a
__device__ __forceinline__ void pair_decode(int p, int& a, int& b) {
    a = (int)((1.0f + sqrtf(1.0f + 8.0f * (float)p)) * 0.5f);
    while (a * (a - 1) / 2 > p) --a;
    while ((a + 1) * a / 2 <= p) ++a;
    b = p - a * (a - 1) / 2;
}

// ---- K1: fused class-blocks (0..N_CLS) + convert blocks (N_CLS..) ----
__global__ __launch_bounds__(256) void conv_pos_kernel(
    const float* __restrict__ emb, const int* __restrict__ labels,
    unsigned short* __restrict__ embb,
    float* __restrict__ pos_min, float* __restrict__ psims,
    int* __restrict__ cls_cnt, int* __restrict__ cls_rows) {
    int t = threadIdx.x;
    if (blockIdx.x >= N_CLS) {
        int i = ((blockIdx.x - N_CLS) * 256 + t) * 4;
        float4 v = *(const float4*)(&emb[i]);
        ushort4 o;
        o.x = f2bf(v.x); o.y = f2bf(v.y); o.z = f2bf(v.z); o.w = f2bf(v.w);
        *(ushort4*)(&embb[i]) = o;
        return;
    }
    int cls = blockIdx.x;
    __shared__ int rs[CLS_CAP];
    __shared__ unsigned int smin[CLS_CAP];
    __shared__ int lcnt;
    if (t == 0) lcnt = 0;
    if (t < CLS_CAP) smin[t] = 0xFF800000u;  // enc(+inf)
    __syncthreads();
    const int4* lab4 = (const int4*)labels;
    for (int i = t; i < B_SIZE / 4; i += 256) {
        int4 L = lab4[i];
        if (L.x == cls) { int p = atomicAdd(&lcnt, 1); if (p < CLS_CAP) rs[p] = 4 * i; }
        if (L.y == cls) { int p = atomicAdd(&lcnt, 1); if (p < CLS_CAP) rs[p] = 4 * i + 1; }
        if (L.z == cls) { int p = atomicAdd(&lcnt, 1); if (p < CLS_CAP) rs[p] = 4 * i + 2; }
        if (L.w == cls) { int p = atomicAdd(&lcnt, 1); if (p < CLS_CAP) rs[p] = 4 * i + 3; }
    }
    __syncthreads();
    int c = min(lcnt, CLS_CAP);
    if (t == 0) cls_cnt[cls] = c;
    if (t < c) cls_rows[cls * CLS_CAP + t] = rs[t];
    int np = c * (c - 1) / 2;
    for (int base = 0; base < np * 8; base += 256) {
        int slot = base + t;
        if (slot < np * 8) {
            int p = slot >> 3, l = slot & 7;   // 8 aligned lanes per pair
            int a, b; pair_decode(p, a, b);
            const float4* pa = (const float4*)(emb + (size_t)rs[a] * D_SIZE) + l * 8;
            const float4* pb = (const float4*)(emb + (size_t)rs[b] * D_SIZE) + l * 8;
            float s = 0.0f;
#pragma unroll
            for (int k = 0; k < 8; ++k) {
                float4 x = pa[k], y = pb[k];
                s = fmaf(x.x, y.x, fmaf(x.y, y.y, fmaf(x.z, y.z, fmaf(x.w, y.w, s))));
            }
            s += __shfl_xor(s, 1, 64);
            s += __shfl_xor(s, 2, 64);
            s += __shfl_xor(s, 4, 64);
            if (l == 0) {
                if (p < PCAP) psims[cls * PCAP + p] = s;
                unsigned int e = enc_f32(s);
                atomicMin(&smin[a], e);
                atomicMin(&smin[b], e);
            }
        }
    }
    __syncthreads();
    if (t < c) pos_min[rs[t]] = dec_f32(smin[t]);
}

// ---- K2: the ONE GEMM (triangular tiles), LDS = exactly 32 KB ----
// part[k*B + row]: m-side writes k=bj (bj>=bi), n-side k=bi (bi<bj) -> each
// k written exactly once per row, unconditionally => no init needed.
// C/D layout (16x16x32): col = lane&15, row = (lane>>4)*4 + reg  [m89/m91]
// Labels read direct from global in the epilogue (L1-broadcast / one line),
// freeing 1 KB of LDS -> 5 blocks/CU instead of 4.
__global__ __launch_bounds__(256) void neg_kernel(
    const unsigned short* __restrict__ embb, const int* __restrict__ labels,
    const float* __restrict__ pos_min,
    float* __restrict__ part_sum, float* __restrict__ part_max)
{
    // triangular tile decode: bj >= bi
    int bt = blockIdx.x;
    int bi = 0, rem = bt;
    while (rem >= (NT - bi)) { rem -= (NT - bi); ++bi; }
    const int bj = bi + rem;
    const int m0 = bi * TM, n0 = bj * TM;
    const bool isdiag = (bi == bj);

    const int tid = threadIdx.x;
    const int lane = tid & 63;
    const int w = tid >> 6;
    const int wm = w >> 1, wn = w & 1;

    __shared__ unsigned char As[2][TM * 64];
    __shared__ unsigned char Bs[2][TM * 64];

    const unsigned short* gA[2];
    const unsigned short* gB[2];
    int lofs[2];
#pragma unroll
    for (int s = 0; s < 2; ++s) {
        int r = w * 32 + s * 16 + (lane >> 2);
        int c = (lane & 3) ^ ((r >> 1) & 3);
        gA[s] = embb + (size_t)(m0 + r) * D_SIZE + c * 8;
        gB[s] = embb + (size_t)(n0 + r) * D_SIZE + c * 8;
        lofs[s] = (w * 32 + s * 16) * 64;
    }
#pragma unroll
    for (int s = 0; s < 2; ++s) { glds16(gA[s], As[0] + lofs[s]); glds16(gB[s], Bs[0] + lofs[s]); }

    const int col = lane & 15;
    const int quad = lane >> 4;
    int aoff[4], boff[4];
#pragma unroll
    for (int f = 0; f < 4; ++f) {
        int ra = wm * 64 + f * 16 + col;
        int rb = wn * 64 + f * 16 + col;
        aoff[f] = ra * 64 + ((quad ^ ((ra >> 1) & 3)) * 16);
        boff[f] = rb * 64 + ((quad ^ ((rb >> 1) & 3)) * 16);
    }

    f32x4 acc[4][4];
#pragma unroll
    for (int fi = 0; fi < 4; ++fi)
#pragma unroll
        for (int fj = 0; fj < 4; ++fj)
            acc[fi][fj] = (f32x4){0.0f, 0.0f, 0.0f, 0.0f};

#pragma unroll
    for (int it = 0; it < D_SIZE / TK; ++it) {
        const int st = it & 1;
        __syncthreads();   // stage st's staging complete
        if (it + 1 < D_SIZE / TK) {
            const int k1 = (it + 1) * TK;
#pragma unroll
            for (int s = 0; s < 2; ++s) {
                glds16(gA[s] + k1, As[st ^ 1] + lofs[s]);
                glds16(gB[s] + k1, Bs[st ^ 1] + lofs[s]);
            }
        }
        bf16x8 af[4], bf[4];
#pragma unroll
        for (int f = 0; f < 4; ++f) {
            af[f] = __builtin_bit_cast(bf16x8, *(const uint4*)(As[st] + aoff[f]));
            bf[f] = __builtin_bit_cast(bf16x8, *(const uint4*)(Bs[st] + boff[f]));
        }
#pragma unroll
        for (int fi = 0; fi < 4; ++fi)
#pragma unroll
            for (int fj = 0; fj < 4; ++fj)
                acc[fi][fj] = __builtin_amdgcn_mfma_f32_16x16x32_bf16(
                    af[fi], bf[fj], acc[fi][fj], 0, 0, 0);
    }

    // ---- epilogue: both sim directions per element, one exp each ----
    // labels direct from global: m-side 4 broadcast addrs per fi; n-side one
    // 64B line per fj per quad-group. L1/L2-resident.
    int ljv[4]; float pmc[4], nsn[4], nmx[4];
#pragma unroll
    for (int fj = 0; fj < 4; ++fj) {
        int cl = wn * 64 + fj * 16 + col;
        ljv[fj] = labels[n0 + cl];
        pmc[fj] = pos_min[n0 + cl] - MARGIN;
        nsn[fj] = 0.0f;
        nmx[fj] = -__builtin_inff();
    }

#pragma unroll
    for (int fi = 0; fi < 4; ++fi) {
        int rl0 = wm * 64 + fi * 16 + quad * 4;
        int gi0 = m0 + rl0;
        int lir[4]; float pmr[4], msn[4], mmx[4];
#pragma unroll
        for (int r = 0; r < 4; ++r) {
            lir[r] = labels[gi0 + r];
            pmr[r] = pos_min[gi0 + r] - MARGIN;
            msn[r] = 0.0f;
            mmx[r] = -__builtin_inff();
        }
#pragma unroll
        for (int fj = 0; fj < 4; ++fj) {
#pragma unroll
            for (int r = 0; r < 4; ++r) {
                float s = acc[fi][fj][r];
                if (lir[r] != ljv[fj]) {
                    float e = __expf(BETA * (s - BASE));
                    mmx[r] = fmaxf(mmx[r], s);
                    if (s > pmr[r]) msn[r] += e;
                    nmx[fj] = fmaxf(nmx[fj], s);
                    if (s > pmc[fj]) nsn[fj] += e;
                }
            }
        }
#pragma unroll
        for (int m = 1; m < 16; m <<= 1) {
#pragma unroll
            for (int r = 0; r < 4; ++r) {
                msn[r] += __shfl_xor(msn[r], m, 64);
                mmx[r] = fmaxf(mmx[r], __shfl_xor(mmx[r], m, 64));
            }
        }
        if (col == 0) {
            *(float4*)(&part_sum[(size_t)bj * B_SIZE + gi0]) =
                make_float4(msn[0], msn[1], msn[2], msn[3]);
            *(float4*)(&part_max[(size_t)bj * B_SIZE + gi0]) =
                make_float4(mmx[0], mmx[1], mmx[2], mmx[3]);
        }
    }
    if (!isdiag) {
#pragma unroll
        for (int m = 16; m < 64; m <<= 1) {
#pragma unroll
            for (int fj = 0; fj < 4; ++fj) {
                nsn[fj] += __shfl_xor(nsn[fj], m, 64);
                nmx[fj] = fmaxf(nmx[fj], __shfl_xor(nmx[fj], m, 64));
            }
        }
        if (quad == 0) {
#pragma unroll
            for (int fj = 0; fj < 4; ++fj) {
                int gj = n0 + wn * 64 + fj * 16 + col;
                part_sum[(size_t)bi * B_SIZE + gj] = nsn[fj];
                part_max[(size_t)bi * B_SIZE + gj] = nmx[fj];
            }
        }
    }
}

// ---- K3: per-class reduce partials (8 lanes/row) + sum_pos + per-class term ----
__global__ __launch_bounds__(256) void final_kernel(
    const float* __restrict__ emb, const int* __restrict__ cls_cnt,
    const int* __restrict__ cls_rows, const float* __restrict__ psims,
    const float* __restrict__ part_sum, const float* __restrict__ part_max,
    float* __restrict__ cls_term, float* __restrict__ cls_valid) {
    int cls = blockIdx.x;
    __shared__ int rs[CLS_CAP];
    __shared__ float snm[CLS_CAP];
    __shared__ float sneg[CLS_CAP];
    __shared__ float ssum[CLS_CAP];
    int t = threadIdx.x;
    int c = min(cls_cnt[cls], CLS_CAP);
    if (t < CLS_CAP) ssum[t] = 0.0f;
    if (t < c) rs[t] = cls_rows[cls * CLS_CAP + t];
    __syncthreads();
    // reduce the 64 neg partials per row; 8 lanes per row for load parallelism
    {
        int l = t & 7;
        for (int rr = t >> 3; rr < c; rr += 32) {
            int row = rs[rr];
            float s = 0.0f, m = -__builtin_inff();
#pragma unroll
            for (int k = 0; k < 8; ++k) {
                s += part_sum[(size_t)(l * 8 + k) * B_SIZE + row];
                m = fmaxf(m, part_max[(size_t)(l * 8 + k) * B_SIZE + row]);
            }
            s += __shfl_xor(s, 1, 64); m = fmaxf(m, __shfl_xor(m, 1, 64));
            s += __shfl_xor(s, 2, 64); m = fmaxf(m, __shfl_xor(m, 2, 64));
            s += __shfl_xor(s, 4, 64); m = fmaxf(m, __shfl_xor(m, 4, 64));
            if (l == 0) { sneg[rr] = s; snm[rr] = m; }
        }
    }
    __syncthreads();
    int np = c * (c - 1) / 2;
    if (np <= PCAP) {
        for (int p = t; p < np; p += 256) {
            float s = psims[cls * PCAP + p];
            int a, b; pair_decode(p, a, b);
            float e = __expf(-ALPHA * (s - BASE));
            if (s - MARGIN < snm[a]) atomicAdd(&ssum[a], e);
            if (s - MARGIN < snm[b]) atomicAdd(&ssum[b], e);
        }
    } else {
        // fallback: recompute dots, 8 lanes per pair
        for (int base = 0; base < np * 8; base += 256) {
            int slot = base + t;
            if (slot < np * 8) {
                int p = slot >> 3, l = slot & 7;
                int a, b; pair_decode(p, a, b);
                const float4* pa = (const float4*)(emb + (size_t)rs[a] * D_SIZE) + l * 8;
                const float4* pb = (const float4*)(emb + (size_t)rs[b] * D_SIZE) + l * 8;
                float s = 0.0f;
#pragma unroll
                for (int k = 0; k < 8; ++k) {
                    float4 x = pa[k], y = pb[k];
                    s = fmaf(x.x, y.x, fmaf(x.y, y.y, fmaf(x.z, y.z, fmaf(x.w, y.w, s))));
                }
                s += __shfl_xor(s, 1, 64);
                s += __shfl_xor(s, 2, 64);
                s += __shfl_xor(s, 4, 64);
                if (l == 0) {
                    float e = __expf(-ALPHA * (s - BASE));
                    if (s - MARGIN < snm[a]) atomicAdd(&ssum[a], e);
                    if (s - MARGIN < snm[b]) atomicAdd(&ssum[b], e);
                }
            }
        }
    }
    __syncthreads();
    // per-class term: rows live on threads 0..c-1 (all in wave 0) -> shfl reduce
    if (t < 64) {
        float term = 0.0f, valid = 0.0f;
        if (t < c) {
            float sp = ssum[t], sn = sneg[t];
            if (sp > 0.0f && sn > 0.0f) {
                term = log1pf(sp) * (1.0f / ALPHA) + log1pf(sn) * (1.0f / BETA);
                valid = 1.0f;
            }
        }
#pragma unroll
        for (int m = 1; m < 64; m <<= 1) {
            term += __shfl_xor(term, m, 64);
            valid += __shfl_xor(valid, m, 64);
        }
        if (t == 0) { cls_term[cls] = term; cls_valid[cls] = valid; }
    }
}

// ---- K4: fold 1024 class terms -> out ----
__global__ __launch_bounds__(256) void finalize_kernel(
    const float* __restrict__ cls_term, const float* __restrict__ cls_valid,
    float* __restrict__ out) {
    __shared__ float st[256];
    __shared__ float sc[256];
    int t = threadIdx.x;
    float tot = 0.0f, cnt = 0.0f;
#pragma unroll
    for (int i = 0; i < N_CLS / 256; ++i) {
        tot += cls_term[i * 256 + t];
        cnt += cls_valid[i * 256 + t];
    }
    st[t] = tot; sc[t] = cnt;
    __syncthreads();
    for (int s = 128; s > 0; s >>= 1) {
        if (t < s) { st[t] += st[t + s]; sc[t] += sc[t + s]; }
        __syncthreads();
    }
    if (t == 0) out[0] = st[0] / fmaxf(sc[0], 1.0f);
}

extern "C" void kernel_launch(void* const* d_in, const int* in_sizes, int n_in,
                              void* d_out, int out_size, void* d_ws, size_t ws_size,
                              hipStream_t stream) {
    const float* emb = (const float*)d_in[0];
    const int* labels = (const int*)d_in[1];
    float* out = (float*)d_out;

    // ws: embb 4MB | part_sum 2MB | part_max 2MB | psims 1MB | cls_rows 256KB |
    //     pos_min 32KB | cls_term 4KB | cls_valid 4KB | cls_cnt 4KB
    unsigned short* embb = (unsigned short*)d_ws;
    float* part_sum = (float*)(embb + (size_t)B_SIZE * D_SIZE);
    float* part_max = part_sum + (size_t)NT * B_SIZE;
    float* psims = part_max + (size_t)NT * B_SIZE;
    int* cls_rows = (int*)(psims + (size_t)N_CLS * PCAP);
    float* pos_min = (float*)(cls_rows + N_CLS * CLS_CAP);
    float* cls_term = pos_min + B_SIZE;
    float* cls_valid = cls_term + N_CLS;
    int* cls_cnt = (int*)(cls_valid + N_CLS);

    conv_pos_kernel<<<dim3(N_CLS + NCONV), dim3(256), 0, stream>>>(
        emb, labels, embb, pos_min, psims, cls_cnt, cls_rows);
    neg_kernel<<<dim3(NBLK), dim3(256), 0, stream>>>(
        embb, labels, pos_min, part_sum, part_max);
    final_kernel<<<dim3(N_CLS), dim3(256), 0, stream>>>(
        emb, cls_cnt, cls_rows, psims, part_sum, part_max, cls_term, cls_valid);
    finalize_kernel<<<dim3(1), dim3(256), 0, stream>>>(cls_term, cls_valid, out);
}